// Round 1
// baseline (804.049 us; speedup 1.0000x reference)
//
#include <hip/hip_runtime.h>
#include <math.h>

#define NN 50000
#define EE 800000
#define ET 850000   // EE + NN (self loops appended)
#define DD 128
#define GG 1000
#define SLOPE 0.2f

// ---------------- CSR build (group edges by dst) ----------------
__global__ void zero_int_k(int* __restrict__ p, int n){
  int i = blockIdx.x*256 + threadIdx.x;
  if (i < n) p[i] = 0;
}

__global__ void count_k(const int* __restrict__ ei, int* __restrict__ cnt){
  int e = blockIdx.x*256 + threadIdx.x;
  if (e < ET){
    int d = (e < EE) ? ei[EE + e] : (e - EE);
    atomicAdd(&cnt[d], 1);
  }
}

__global__ __launch_bounds__(1024) void scan_k(const int* __restrict__ cnt,
                                               int* __restrict__ row_start,
                                               int* __restrict__ cursor){
  __shared__ int part[1024];
  int tid = threadIdx.x;
  const int CH = (NN + 1023)/1024;   // 49
  int beg = tid*CH;
  int s = 0;
  for (int i=0;i<CH;++i){ int n=beg+i; if(n<NN) s += cnt[n]; }
  part[tid] = s;
  __syncthreads();
  for (int off=1; off<1024; off<<=1){
    int v = (tid>=off) ? part[tid-off] : 0;
    __syncthreads();
    part[tid] += v;
    __syncthreads();
  }
  int run = tid ? part[tid-1] : 0;
  for (int i=0;i<CH;++i){
    int n = beg+i;
    if (n < NN){ row_start[n] = run; cursor[n] = run; run += cnt[n]; }
  }
  if (tid == 1023) row_start[NN] = run;
}

__global__ void fill_k(const int* __restrict__ ei, int* __restrict__ cursor,
                       int* __restrict__ srcs){
  int e = blockIdx.x*256 + threadIdx.x;
  if (e < ET){
    int s, d;
    if (e < EE){ s = ei[e]; d = ei[EE + e]; }
    else       { s = e - EE; d = s; }
    int pos = atomicAdd(&cursor[d], 1);
    srcs[pos] = s;
  }
}

// graph boundaries from sorted batchs
__global__ void gstart_k(const int* __restrict__ batchs, int* __restrict__ gstart){
  int n = blockIdx.x*256 + threadIdx.x;
  if (n < NN){
    int b = batchs[n];
    int prev = n ? batchs[n-1] : -1;
    for (int g = prev+1; g <= b; ++g) gstart[g] = n;
    if (n == NN-1){
      for (int g = b+1; g <= GG; ++g) gstart[g] = NN;
    }
  }
}

// ---------------- GEMM: C[N,128] = A[N,128] @ W[128,128] ----------------
// 64 rows/block, A transposed into LDS, W staged 64 cols at a time.
__global__ __launch_bounds__(256) void gemm128_k(const float* __restrict__ A,
                                                 const float* __restrict__ W,
                                                 float* __restrict__ C){
  __shared__ float Alt[DD*64];   // [k][r]  32KB
  __shared__ float Wl[DD*64];    // [k][c]  32KB
  int tid = threadIdx.x;
  int rbase = blockIdx.x*64;
  // load + transpose A tile (conflict-free LDS writes; global 16B/lane)
  for (int it=0; it<8; ++it){
    int i = it*256 + tid;
    int r = i & 63;
    int c4 = i >> 6;
    float4 v = {0.f,0.f,0.f,0.f};
    if (rbase + r < NN) v = *(const float4*)(A + (size_t)(rbase+r)*DD + c4*4);
    Alt[(c4*4+0)*64 + r] = v.x;
    Alt[(c4*4+1)*64 + r] = v.y;
    Alt[(c4*4+2)*64 + r] = v.z;
    Alt[(c4*4+3)*64 + r] = v.w;
  }
  int ry = tid >> 4, cx = tid & 15;
  for (int jt=0; jt<2; ++jt){
    __syncthreads();
    for (int it=0; it<8; ++it){
      int i = it*256 + tid;
      int k = i >> 4, c4 = i & 15;
      *(float4*)(Wl + k*64 + c4*4) = *(const float4*)(W + k*DD + jt*64 + c4*4);
    }
    __syncthreads();
    float acc[4][4] = {};
    #pragma unroll 8
    for (int k=0;k<DD;++k){
      float4 av = *(const float4*)(Alt + k*64 + ry*4);
      float4 wv = *(const float4*)(Wl + k*64 + cx*4);
      float a[4] = {av.x, av.y, av.z, av.w};
      float b[4] = {wv.x, wv.y, wv.z, wv.w};
      #pragma unroll
      for (int ii=0;ii<4;++ii)
        #pragma unroll
        for (int jj=0;jj<4;++jj)
          acc[ii][jj] += a[ii]*b[jj];
    }
    #pragma unroll
    for (int ii=0;ii<4;++ii){
      int r = rbase + ry*4 + ii;
      if (r < NN){
        float4 o = {acc[ii][0], acc[ii][1], acc[ii][2], acc[ii][3]};
        *(float4*)(C + (size_t)r*DD + jt*64 + cx*4) = o;
      }
    }
  }
}

// hs[n] = h[n].as, hd[n] = h[n].ad  (one wave per node)
__global__ __launch_bounds__(256) void rowdot_k(const float* __restrict__ h,
                                                const float* __restrict__ as,
                                                const float* __restrict__ ad,
                                                float* __restrict__ hs, float* __restrict__ hd){
  int node = blockIdx.x*4 + (threadIdx.x >> 6);
  int lane = threadIdx.x & 63;
  if (node >= NN) return;
  float2 hv = *(const float2*)(h + (size_t)node*DD + lane*2);
  float2 a1 = *(const float2*)(as + lane*2);
  float2 a2 = *(const float2*)(ad + lane*2);
  float s1 = hv.x*a1.x + hv.y*a1.y;
  float s2 = hv.x*a2.x + hv.y*a2.y;
  #pragma unroll
  for (int o=32;o;o>>=1){ s1 += __shfl_xor(s1,o); s2 += __shfl_xor(s2,o); }
  if (lane == 0){ hs[node] = s1; hd[node] = s2; }
}

// fused softmax-attention aggregation: one wave per dst node, online softmax,
// out[n] = relu( sum_i alpha_i * h[src_i] + b )
__global__ __launch_bounds__(256) void gat_agg_k(const float* __restrict__ h,
                                                 const float* __restrict__ hs,
                                                 const float* __restrict__ hd,
                                                 const int* __restrict__ row_start,
                                                 const int* __restrict__ srcs,
                                                 const float* __restrict__ bias,
                                                 float* __restrict__ out){
  int node = blockIdx.x*4 + (threadIdx.x >> 6);
  int lane = threadIdx.x & 63;
  if (node >= NN) return;
  int beg = row_start[node], end = row_start[node+1];
  float hdn = hd[node];
  float m = -INFINITY, denom = 0.f;
  float accx = 0.f, accy = 0.f;
  for (int c=beg; c<end; c+=64){
    int nc = min(64, end-c);
    float e = -INFINITY; int src = 0;
    if (lane < nc){
      src = srcs[c+lane];
      float t = hs[src] + hdn;
      e = (t >= 0.f) ? t : SLOPE*t;
    }
    float cm = e;
    #pragma unroll
    for (int o=32;o;o>>=1) cm = fmaxf(cm, __shfl_xor(cm,o));
    float nm = fmaxf(m, cm);
    float w = (lane < nc) ? expf(e - nm) : 0.f;
    float cs = w;
    #pragma unroll
    for (int o=32;o;o>>=1) cs += __shfl_xor(cs,o);
    float scale = expf(m - nm);       // 0 on first chunk (m=-inf)
    denom = denom*scale + cs;
    accx *= scale; accy *= scale;
    m = nm;
    for (int i=0;i<nc;++i){
      float wi = __shfl(w, i);
      int si = __shfl(src, i);
      float2 hv = *(const float2*)(h + (size_t)si*DD + lane*2);
      accx += wi*hv.x; accy += wi*hv.y;
    }
  }
  float inv = 1.f/denom;
  float2 b2 = *(const float2*)(bias + lane*2);
  float2 o2;
  o2.x = fmaxf(accx*inv + b2.x, 0.f);
  o2.y = fmaxf(accy*inv + b2.y, 0.f);
  *(float2*)(out + (size_t)node*DD + lane*2) = o2;
}

// global_add_pool via sorted-batch ranges
__global__ __launch_bounds__(128) void pool_k(const float* __restrict__ h,
                                              const int* __restrict__ gstart,
                                              float* __restrict__ g){
  int gr = blockIdx.x, j = threadIdx.x;
  int beg = gstart[gr], end = gstart[gr+1];
  float s = 0.f;
  for (int n=beg; n<end; ++n) s += h[(size_t)n*DD + j];
  g[gr*DD + j] = s;
}

// out = relu(in @ W + b), in:[G,128] W:[128,128]
__global__ __launch_bounds__(128) void fc_relu_k(const float* __restrict__ in,
                                                 const float* __restrict__ W,
                                                 const float* __restrict__ b,
                                                 float* __restrict__ out){
  int r = blockIdx.x, j = threadIdx.x;
  const float* row = in + (size_t)r*DD;
  float acc = 0.f;
  #pragma unroll 8
  for (int k=0;k<DD;++k) acc += row[k]*W[k*DD + j];
  out[(size_t)r*DD + j] = fmaxf(acc + b[j], 0.f);
}

// z = relu(cat(y, energy) @ W + b) + y   (W:[129,128])
__global__ __launch_bounds__(128) void fc1_k(const float* __restrict__ y,
                                             const float* __restrict__ energy,
                                             const float* __restrict__ W,
                                             const float* __restrict__ b,
                                             float* __restrict__ out){
  int r = blockIdx.x, j = threadIdx.x;
  const float* row = y + (size_t)r*DD;
  float acc = 0.f;
  #pragma unroll 8
  for (int k=0;k<DD;++k) acc += row[k]*W[k*DD + j];
  acc += energy[r]*W[DD*DD + j];
  float v = fmaxf(acc + b[j], 0.f);
  out[(size_t)r*DD + j] = v + row[j];
}

// logits = z @ W[128,2] + b; out = log_softmax (one wave per graph)
__global__ __launch_bounds__(64) void head_k(const float* __restrict__ z,
                                             const float* __restrict__ W,
                                             const float* __restrict__ b,
                                             float* __restrict__ out){
  int r = blockIdx.x, lane = threadIdx.x;
  float z0 = z[(size_t)r*DD + lane];
  float z1 = z[(size_t)r*DD + 64 + lane];
  float a0 = z0*W[lane*2]        + z1*W[(64+lane)*2];
  float a1 = z0*W[lane*2 + 1]    + z1*W[(64+lane)*2 + 1];
  #pragma unroll
  for (int o=32;o;o>>=1){ a0 += __shfl_xor(a0,o); a1 += __shfl_xor(a1,o); }
  if (lane == 0){
    float l0 = a0 + b[0], l1 = a1 + b[1];
    float mx = fmaxf(l0, l1);
    float lse = mx + logf(expf(l0-mx) + expf(l1-mx));
    out[r*2]   = l0 - lse;
    out[r*2+1] = l1 - lse;
  }
}

extern "C" void kernel_launch(void* const* d_in, const int* in_sizes, int n_in,
                              void* d_out, int out_size, void* d_ws, size_t ws_size,
                              hipStream_t stream) {
  const float* x      = (const float*)d_in[0];
  const float* energy = (const float*)d_in[1];
  const float* W1     = (const float*)d_in[2];
  const float* as1    = (const float*)d_in[3];
  const float* ad1    = (const float*)d_in[4];
  const float* b1     = (const float*)d_in[5];
  const float* Ws     = (const float*)d_in[6];
  const float* ass    = (const float*)d_in[7];
  const float* ads    = (const float*)d_in[8];
  const float* bs     = (const float*)d_in[9];
  const float* lin0_W = (const float*)d_in[10];
  const float* lin0_b = (const float*)d_in[11];
  const float* lin1_W = (const float*)d_in[12];
  const float* lin1_b = (const float*)d_in[13];
  const float* lins_W = (const float*)d_in[14];
  const float* lins_b = (const float*)d_in[15];
  const float* lin3_W = (const float*)d_in[16];
  const float* lin3_b = (const float*)d_in[17];
  const int*   ei     = (const int*)d_in[18];
  const int*   batchs = (const int*)d_in[19];
  float* out = (float*)d_out;

  char* wp = (char*)d_ws;
  auto alloc = [&](size_t bytes)->void*{
    void* p = (void*)wp;
    wp += (bytes + 255) & ~(size_t)255;
    return p;
  };
  float* hA        = (float*)alloc((size_t)NN*DD*4);
  float* hB        = (float*)alloc((size_t)NN*DD*4);
  float* hs        = (float*)alloc((size_t)NN*4);
  float* hd        = (float*)alloc((size_t)NN*4);
  float* gbuf      = (float*)alloc((size_t)GG*DD*4);
  float* ybuf      = (float*)alloc((size_t)GG*DD*4);
  float* zbuf      = (float*)alloc((size_t)GG*DD*4);
  int*   cnt       = (int*)alloc((size_t)NN*4);
  int*   row_start = (int*)alloc((size_t)(NN+1)*4);
  int*   cursor    = (int*)alloc((size_t)NN*4);
  int*   srcs      = (int*)alloc((size_t)ET*4);
  int*   gstart    = (int*)alloc((size_t)(GG+1)*4);

  const int NB_N  = (NN + 255)/256;     // 196
  const int NB_E  = (ET + 255)/256;     // 3321
  const int NB_W  = (NN + 3)/4;         // 12500 (wave per node)
  const int NB_G  = (NN + 63)/64;       // 782 gemm blocks

  // CSR + graph boundaries (per call: ws is re-poisoned each launch)
  zero_int_k<<<NB_N, 256, 0, stream>>>(cnt, NN);
  count_k<<<NB_E, 256, 0, stream>>>(ei, cnt);
  scan_k<<<1, 1024, 0, stream>>>(cnt, row_start, cursor);
  fill_k<<<NB_E, 256, 0, stream>>>(ei, cursor, srcs);
  gstart_k<<<NB_N, 256, 0, stream>>>(batchs, gstart);

  // 4 GAT layers
  const float* hin = x;
  for (int l=0; l<4; ++l){
    const float* Wl  = (l==0) ? W1  : Ws  + (size_t)(l-1)*DD*DD;
    const float* asl = (l==0) ? as1 : ass + (size_t)(l-1)*DD;
    const float* adl = (l==0) ? ad1 : ads + (size_t)(l-1)*DD;
    const float* bl  = (l==0) ? b1  : bs  + (size_t)(l-1)*DD;
    gemm128_k<<<NB_G, 256, 0, stream>>>(hin, Wl, hB);
    rowdot_k<<<NB_W, 256, 0, stream>>>(hB, asl, adl, hs, hd);
    gat_agg_k<<<NB_W, 256, 0, stream>>>(hB, hs, hd, row_start, srcs, bl, hA);
    hin = hA;
  }

  // pooling + FC head
  pool_k<<<GG, 128, 0, stream>>>(hA, gstart, gbuf);
  fc_relu_k<<<GG, 128, 0, stream>>>(gbuf, lin0_W, lin0_b, ybuf);
  fc1_k<<<GG, 128, 0, stream>>>(ybuf, energy, lin1_W, lin1_b, zbuf);
  fc_relu_k<<<GG, 128, 0, stream>>>(zbuf, lins_W, lins_b, gbuf);  // reuse gbuf as z2
  head_k<<<GG, 64, 0, stream>>>(gbuf, lin3_W, lin3_b, out);
}

// Round 2
// 629.752 us; speedup vs baseline: 1.2768x; 1.2768x over previous
//
#include <hip/hip_runtime.h>
#include <math.h>

#define NN 50000
#define EE 800000
#define ET 850000   // EE + NN (self loops appended)
#define DD 128
#define GG 1000
#define SLOPE 0.2f

// ---------------- CSR build (group edges by dst) ----------------
__global__ void zero_int_k(int* __restrict__ p, int n){
  int i = blockIdx.x*256 + threadIdx.x;
  if (i < n) p[i] = 0;
}

__global__ void count_k(const int* __restrict__ ei, int* __restrict__ cnt){
  int e = blockIdx.x*256 + threadIdx.x;
  if (e < ET){
    int d = (e < EE) ? ei[EE + e] : (e - EE);
    atomicAdd(&cnt[d], 1);
  }
}

// hierarchical exclusive scan of cnt[NN] -> row_start / cursor
__global__ __launch_bounds__(256) void blocksum_k(const int* __restrict__ cnt,
                                                  int* __restrict__ bsum){
  int i = blockIdx.x*256 + threadIdx.x;
  int v = (i < NN) ? cnt[i] : 0;
  #pragma unroll
  for (int o=32;o;o>>=1) v += __shfl_xor(v,o);
  __shared__ int ws[4];
  if ((threadIdx.x & 63) == 0) ws[threadIdx.x>>6] = v;
  __syncthreads();
  if (threadIdx.x == 0) bsum[blockIdx.x] = ws[0]+ws[1]+ws[2]+ws[3];
}

__global__ __launch_bounds__(256) void scanb_k(int* __restrict__ bsum, int nb){
  int tid = threadIdx.x;
  int v = (tid < nb) ? bsum[tid] : 0;
  int lane = tid & 63, wv = tid >> 6;
  int s = v;
  #pragma unroll
  for (int o=1;o<64;o<<=1){ int t = __shfl_up(s,o); if (lane>=o) s += t; }
  __shared__ int ws[4];
  if (lane == 63) ws[wv] = s;
  __syncthreads();
  int woff = 0;
  for (int k=0;k<wv;++k) woff += ws[k];
  if (tid < nb) bsum[tid] = s - v + woff;   // exclusive prefix
}

__global__ __launch_bounds__(256) void scatter_k(const int* __restrict__ cnt,
                                                 const int* __restrict__ bsum,
                                                 int* __restrict__ row_start,
                                                 int* __restrict__ cursor){
  int i = blockIdx.x*256 + threadIdx.x;
  int v = (i < NN) ? cnt[i] : 0;
  int lane = threadIdx.x & 63, wv = threadIdx.x >> 6;
  int s = v;
  #pragma unroll
  for (int o=1;o<64;o<<=1){ int t = __shfl_up(s,o); if (lane>=o) s += t; }
  __shared__ int ws[4];
  if (lane == 63) ws[wv] = s;
  __syncthreads();
  int woff = 0;
  for (int k=0;k<wv;++k) woff += ws[k];
  int off = s - v + woff + bsum[blockIdx.x];
  if (i < NN){ row_start[i] = off; cursor[i] = off; }
  if (i == 0) row_start[NN] = ET;
}

__global__ void fill_k(const int* __restrict__ ei, int* __restrict__ cursor,
                       int* __restrict__ srcs){
  int e = blockIdx.x*256 + threadIdx.x;
  if (e < ET){
    int s, d;
    if (e < EE){ s = ei[e]; d = ei[EE + e]; }
    else       { s = e - EE; d = s; }
    int pos = atomicAdd(&cursor[d], 1);
    srcs[pos] = s;
  }
}

// graph boundaries from sorted batchs
__global__ void gstart_k(const int* __restrict__ batchs, int* __restrict__ gstart){
  int n = blockIdx.x*256 + threadIdx.x;
  if (n < NN){
    int b = batchs[n];
    int prev = n ? batchs[n-1] : -1;
    for (int g = prev+1; g <= b; ++g) gstart[g] = n;
    if (n == NN-1){
      for (int g = b+1; g <= GG; ++g) gstart[g] = NN;
    }
  }
}

// ---------------- GEMM: C[N,128] = A[N,128] @ W[128,128] ----------------
// 64 rows/block; fused epilogue also computes hs[r]=C[r].as, hd[r]=C[r].ad
__global__ __launch_bounds__(256) void gemm128_k(const float* __restrict__ A,
                                                 const float* __restrict__ W,
                                                 const float* __restrict__ as,
                                                 const float* __restrict__ ad,
                                                 float* __restrict__ C,
                                                 float* __restrict__ hs,
                                                 float* __restrict__ hd){
  __shared__ float Alt[DD*64];   // [k][r]  32KB
  __shared__ float Wl[DD*64];    // [k][c]  32KB
  int tid = threadIdx.x;
  int rbase = blockIdx.x*64;
  for (int it=0; it<8; ++it){
    int i = it*256 + tid;
    int r = i & 63;
    int c4 = i >> 6;
    float4 v = {0.f,0.f,0.f,0.f};
    if (rbase + r < NN) v = *(const float4*)(A + (size_t)(rbase+r)*DD + c4*4);
    Alt[(c4*4+0)*64 + r] = v.x;
    Alt[(c4*4+1)*64 + r] = v.y;
    Alt[(c4*4+2)*64 + r] = v.z;
    Alt[(c4*4+3)*64 + r] = v.w;
  }
  int ry = tid >> 4, cx = tid & 15;
  float hsum[4] = {0.f,0.f,0.f,0.f};
  float hdsum[4] = {0.f,0.f,0.f,0.f};
  for (int jt=0; jt<2; ++jt){
    __syncthreads();
    for (int it=0; it<8; ++it){
      int i = it*256 + tid;
      int k = i >> 4, c4 = i & 15;
      *(float4*)(Wl + k*64 + c4*4) = *(const float4*)(W + k*DD + jt*64 + c4*4);
    }
    __syncthreads();
    float acc[4][4] = {};
    #pragma unroll 8
    for (int k=0;k<DD;++k){
      float4 av = *(const float4*)(Alt + k*64 + ry*4);
      float4 wv = *(const float4*)(Wl + k*64 + cx*4);
      float a[4] = {av.x, av.y, av.z, av.w};
      float b[4] = {wv.x, wv.y, wv.z, wv.w};
      #pragma unroll
      for (int ii=0;ii<4;++ii)
        #pragma unroll
        for (int jj=0;jj<4;++jj)
          acc[ii][jj] += a[ii]*b[jj];
    }
    // fused rowdot: partial dots of this 64-col slab with a_src/a_dst
    float4 a_s = *(const float4*)(as + jt*64 + cx*4);
    float4 a_d = *(const float4*)(ad + jt*64 + cx*4);
    #pragma unroll
    for (int ii=0;ii<4;++ii){
      float ds = acc[ii][0]*a_s.x + acc[ii][1]*a_s.y + acc[ii][2]*a_s.z + acc[ii][3]*a_s.w;
      float dd = acc[ii][0]*a_d.x + acc[ii][1]*a_d.y + acc[ii][2]*a_d.z + acc[ii][3]*a_d.w;
      #pragma unroll
      for (int o=1;o<16;o<<=1){ ds += __shfl_xor(ds,o); dd += __shfl_xor(dd,o); }
      hsum[ii] += ds; hdsum[ii] += dd;
    }
    #pragma unroll
    for (int ii=0;ii<4;++ii){
      int r = rbase + ry*4 + ii;
      if (r < NN){
        float4 o = {acc[ii][0], acc[ii][1], acc[ii][2], acc[ii][3]};
        *(float4*)(C + (size_t)r*DD + jt*64 + cx*4) = o;
      }
    }
  }
  if (cx == 0){
    #pragma unroll
    for (int ii=0;ii<4;++ii){
      int r = rbase + ry*4 + ii;
      if (r < NN){ hs[r] = hsum[ii]; hd[r] = hdsum[ii]; }
    }
  }
}

// fused softmax-attention aggregation: one wave per dst node, online softmax.
// Half-wave parity split: lanes 0-31 accumulate even-index edges, 32-63 odd,
// each half loading full 128-f rows as 32 x float4. m/denom stay full-wave.
__global__ __launch_bounds__(256) void gat_agg_k(const float* __restrict__ h,
                                                 const float* __restrict__ hs,
                                                 const float* __restrict__ hd,
                                                 const int* __restrict__ row_start,
                                                 const int* __restrict__ srcs,
                                                 const float* __restrict__ bias,
                                                 float* __restrict__ out){
  int node = blockIdx.x*4 + (threadIdx.x >> 6);
  int lane = threadIdx.x & 63;
  if (node >= NN) return;
  int half = lane >> 5;
  int hl   = lane & 31;
  int beg = row_start[node], end = row_start[node+1];
  float hdn = hd[node];
  float m = -INFINITY, denom = 0.f;
  float4 acc = {0.f,0.f,0.f,0.f};
  for (int c=beg; c<end; c+=64){
    int nc = min(64, end-c);
    float e = -INFINITY; int src = 0;
    if (lane < nc){
      src = srcs[c+lane];
      float t = hs[src] + hdn;
      e = (t >= 0.f) ? t : SLOPE*t;
    }
    float cm = e;
    #pragma unroll
    for (int o=32;o;o>>=1) cm = fmaxf(cm, __shfl_xor(cm,o));
    float nm = fmaxf(m, cm);
    float w = (lane < nc) ? expf(e - nm) : 0.f;
    float cs = w;
    #pragma unroll
    for (int o=32;o;o>>=1) cs += __shfl_xor(cs,o);
    float scale = expf(m - nm);       // 0 on first chunk (m=-inf, nm finite)
    denom = denom*scale + cs;
    acc.x *= scale; acc.y *= scale; acc.z *= scale; acc.w *= scale;
    m = nm;
    int nh = (nc + 1 - half) >> 1;    // edges with chunk-index parity == half
    for (int i=0;i<nh;++i){
      int j = 2*i + half;
      float wi = __shfl(w, j);
      int   si = __shfl(src, j);
      float4 hv = *(const float4*)(h + (size_t)si*DD + hl*4);
      acc.x += wi*hv.x; acc.y += wi*hv.y; acc.z += wi*hv.z; acc.w += wi*hv.w;
    }
  }
  // merge halves (common m/denom, acc split by edge parity)
  acc.x += __shfl_xor(acc.x, 32);
  acc.y += __shfl_xor(acc.y, 32);
  acc.z += __shfl_xor(acc.z, 32);
  acc.w += __shfl_xor(acc.w, 32);
  if (half == 0){
    float inv = 1.f/denom;
    float4 b4 = *(const float4*)(bias + hl*4);
    float4 o4;
    o4.x = fmaxf(acc.x*inv + b4.x, 0.f);
    o4.y = fmaxf(acc.y*inv + b4.y, 0.f);
    o4.z = fmaxf(acc.z*inv + b4.z, 0.f);
    o4.w = fmaxf(acc.w*inv + b4.w, 0.f);
    *(float4*)(out + (size_t)node*DD + hl*4) = o4;
  }
}

// global_add_pool via sorted-batch ranges
__global__ __launch_bounds__(128) void pool_k(const float* __restrict__ h,
                                              const int* __restrict__ gstart,
                                              float* __restrict__ g){
  int gr = blockIdx.x, j = threadIdx.x;
  int beg = gstart[gr], end = gstart[gr+1];
  float s = 0.f;
  for (int n=beg; n<end; ++n) s += h[(size_t)n*DD + j];
  g[gr*DD + j] = s;
}

// out = relu(in @ W + b), in:[G,128] W:[128,128]
__global__ __launch_bounds__(128) void fc_relu_k(const float* __restrict__ in,
                                                 const float* __restrict__ W,
                                                 const float* __restrict__ b,
                                                 float* __restrict__ out){
  int r = blockIdx.x, j = threadIdx.x;
  const float* row = in + (size_t)r*DD;
  float acc = 0.f;
  #pragma unroll 8
  for (int k=0;k<DD;++k) acc += row[k]*W[k*DD + j];
  out[(size_t)r*DD + j] = fmaxf(acc + b[j], 0.f);
}

// z = relu(cat(y, energy) @ W + b) + y   (W:[129,128])
__global__ __launch_bounds__(128) void fc1_k(const float* __restrict__ y,
                                             const float* __restrict__ energy,
                                             const float* __restrict__ W,
                                             const float* __restrict__ b,
                                             float* __restrict__ out){
  int r = blockIdx.x, j = threadIdx.x;
  const float* row = y + (size_t)r*DD;
  float acc = 0.f;
  #pragma unroll 8
  for (int k=0;k<DD;++k) acc += row[k]*W[k*DD + j];
  acc += energy[r]*W[DD*DD + j];
  float v = fmaxf(acc + b[j], 0.f);
  out[(size_t)r*DD + j] = v + row[j];
}

// logits = z @ W[128,2] + b; out = log_softmax (one wave per graph)
__global__ __launch_bounds__(64) void head_k(const float* __restrict__ z,
                                             const float* __restrict__ W,
                                             const float* __restrict__ b,
                                             float* __restrict__ out){
  int r = blockIdx.x, lane = threadIdx.x;
  float z0 = z[(size_t)r*DD + lane];
  float z1 = z[(size_t)r*DD + 64 + lane];
  float a0 = z0*W[lane*2]        + z1*W[(64+lane)*2];
  float a1 = z0*W[lane*2 + 1]    + z1*W[(64+lane)*2 + 1];
  #pragma unroll
  for (int o=32;o;o>>=1){ a0 += __shfl_xor(a0,o); a1 += __shfl_xor(a1,o); }
  if (lane == 0){
    float l0 = a0 + b[0], l1 = a1 + b[1];
    float mx = fmaxf(l0, l1);
    float lse = mx + logf(expf(l0-mx) + expf(l1-mx));
    out[r*2]   = l0 - lse;
    out[r*2+1] = l1 - lse;
  }
}

extern "C" void kernel_launch(void* const* d_in, const int* in_sizes, int n_in,
                              void* d_out, int out_size, void* d_ws, size_t ws_size,
                              hipStream_t stream) {
  const float* x      = (const float*)d_in[0];
  const float* energy = (const float*)d_in[1];
  const float* W1     = (const float*)d_in[2];
  const float* as1    = (const float*)d_in[3];
  const float* ad1    = (const float*)d_in[4];
  const float* b1     = (const float*)d_in[5];
  const float* Ws     = (const float*)d_in[6];
  const float* ass    = (const float*)d_in[7];
  const float* ads    = (const float*)d_in[8];
  const float* bs     = (const float*)d_in[9];
  const float* lin0_W = (const float*)d_in[10];
  const float* lin0_b = (const float*)d_in[11];
  const float* lin1_W = (const float*)d_in[12];
  const float* lin1_b = (const float*)d_in[13];
  const float* lins_W = (const float*)d_in[14];
  const float* lins_b = (const float*)d_in[15];
  const float* lin3_W = (const float*)d_in[16];
  const float* lin3_b = (const float*)d_in[17];
  const int*   ei     = (const int*)d_in[18];
  const int*   batchs = (const int*)d_in[19];
  float* out = (float*)d_out;

  char* wp = (char*)d_ws;
  auto alloc = [&](size_t bytes)->void*{
    void* p = (void*)wp;
    wp += (bytes + 255) & ~(size_t)255;
    return p;
  };
  float* hA        = (float*)alloc((size_t)NN*DD*4);
  float* hB        = (float*)alloc((size_t)NN*DD*4);
  float* hs        = (float*)alloc((size_t)NN*4);
  float* hd        = (float*)alloc((size_t)NN*4);
  float* gbuf      = (float*)alloc((size_t)GG*DD*4);
  float* ybuf      = (float*)alloc((size_t)GG*DD*4);
  float* zbuf      = (float*)alloc((size_t)GG*DD*4);
  int*   cnt       = (int*)alloc((size_t)NN*4);
  int*   row_start = (int*)alloc((size_t)(NN+1)*4);
  int*   cursor    = (int*)alloc((size_t)NN*4);
  int*   srcs      = (int*)alloc((size_t)ET*4);
  int*   gstart    = (int*)alloc((size_t)(GG+1)*4);
  int*   bsum      = (int*)alloc((size_t)256*4);

  const int NB_N  = (NN + 255)/256;     // 196
  const int NB_E  = (ET + 255)/256;     // 3321
  const int NB_W  = (NN + 3)/4;         // 12500 (wave per node)
  const int NB_G  = (NN + 63)/64;       // 782 gemm blocks

  // CSR + graph boundaries
  zero_int_k<<<NB_N, 256, 0, stream>>>(cnt, NN);
  count_k<<<NB_E, 256, 0, stream>>>(ei, cnt);
  blocksum_k<<<NB_N, 256, 0, stream>>>(cnt, bsum);
  scanb_k<<<1, 256, 0, stream>>>(bsum, NB_N);
  scatter_k<<<NB_N, 256, 0, stream>>>(cnt, bsum, row_start, cursor);
  fill_k<<<NB_E, 256, 0, stream>>>(ei, cursor, srcs);
  gstart_k<<<NB_N, 256, 0, stream>>>(batchs, gstart);

  // 4 GAT layers
  const float* hin = x;
  for (int l=0; l<4; ++l){
    const float* Wl  = (l==0) ? W1  : Ws  + (size_t)(l-1)*DD*DD;
    const float* asl = (l==0) ? as1 : ass + (size_t)(l-1)*DD;
    const float* adl = (l==0) ? ad1 : ads + (size_t)(l-1)*DD;
    const float* bl  = (l==0) ? b1  : bs  + (size_t)(l-1)*DD;
    gemm128_k<<<NB_G, 256, 0, stream>>>(hin, Wl, asl, adl, hB, hs, hd);
    gat_agg_k<<<NB_W, 256, 0, stream>>>(hB, hs, hd, row_start, srcs, bl, hA);
    hin = hA;
  }

  // pooling + FC head
  pool_k<<<GG, 128, 0, stream>>>(hA, gstart, gbuf);
  fc_relu_k<<<GG, 128, 0, stream>>>(gbuf, lin0_W, lin0_b, ybuf);
  fc1_k<<<GG, 128, 0, stream>>>(ybuf, energy, lin1_W, lin1_b, zbuf);
  fc_relu_k<<<GG, 128, 0, stream>>>(zbuf, lins_W, lins_b, gbuf);  // z2
  head_k<<<GG, 64, 0, stream>>>(gbuf, lin3_W, lin3_b, out);
}

// Round 5
// 587.290 us; speedup vs baseline: 1.3691x; 1.0723x over previous
//
#include <hip/hip_runtime.h>
#include <math.h>

#define NN 50000
#define EE 800000
#define ET 850000   // EE + NN (self loops appended)
#define DD 128
#define GG 1000
#define SLOPE 0.2f

typedef unsigned int  u32;
typedef unsigned short u16;

// fp16 pack/unpack (hardware cvt, round-to-nearest-even)
__device__ __forceinline__ u16 f2h(float f){
  return __builtin_bit_cast(unsigned short, (_Float16)f);
}
__device__ __forceinline__ float hlo(u32 d){
  return (float)__builtin_bit_cast(_Float16, (unsigned short)(d & 0xFFFFu));
}
__device__ __forceinline__ float hhi(u32 d){
  return (float)__builtin_bit_cast(_Float16, (unsigned short)(d >> 16));
}

// ---------------- init: cnt=0 + graph boundaries ----------------
__global__ void init_k(const int* __restrict__ batchs, int* __restrict__ cnt,
                       int* __restrict__ gstart){
  int n = blockIdx.x*256 + threadIdx.x;
  if (n < NN){
    cnt[n] = 0;
    int b = batchs[n];
    int prev = n ? batchs[n-1] : -1;
    for (int g = prev+1; g <= b; ++g) gstart[g] = n;
    if (n == NN-1){
      for (int g = b+1; g <= GG; ++g) gstart[g] = NN;
    }
  }
}

__global__ void count_k(const int* __restrict__ ei, int* __restrict__ cnt){
  int e = blockIdx.x*256 + threadIdx.x;
  if (e < ET){
    int d = (e < EE) ? ei[EE + e] : (e - EE);
    atomicAdd(&cnt[d], 1);
  }
}

__global__ __launch_bounds__(256) void blocksum_k(const int* __restrict__ cnt,
                                                  int* __restrict__ bsum){
  int i = blockIdx.x*256 + threadIdx.x;
  int v = (i < NN) ? cnt[i] : 0;
  #pragma unroll
  for (int o=32;o;o>>=1) v += __shfl_xor(v,o);
  __shared__ int ws[4];
  if ((threadIdx.x & 63) == 0) ws[threadIdx.x>>6] = v;
  __syncthreads();
  if (threadIdx.x == 0) bsum[blockIdx.x] = ws[0]+ws[1]+ws[2]+ws[3];
}

__global__ __launch_bounds__(256) void scanb_k(int* __restrict__ bsum, int nb){
  int tid = threadIdx.x;
  int v = (tid < nb) ? bsum[tid] : 0;
  int lane = tid & 63, wv = tid >> 6;
  int s = v;
  #pragma unroll
  for (int o=1;o<64;o<<=1){ int t = __shfl_up(s,o); if (lane>=o) s += t; }
  __shared__ int ws[4];
  if (lane == 63) ws[wv] = s;
  __syncthreads();
  int woff = 0;
  for (int k=0;k<wv;++k) woff += ws[k];
  if (tid < nb) bsum[tid] = s - v + woff;   // exclusive prefix
}

__global__ __launch_bounds__(256) void scatter_k(const int* __restrict__ cnt,
                                                 const int* __restrict__ bsum,
                                                 int* __restrict__ row_start,
                                                 int* __restrict__ cursor){
  int i = blockIdx.x*256 + threadIdx.x;
  int v = (i < NN) ? cnt[i] : 0;
  int lane = threadIdx.x & 63, wv = threadIdx.x >> 6;
  int s = v;
  #pragma unroll
  for (int o=1;o<64;o<<=1){ int t = __shfl_up(s,o); if (lane>=o) s += t; }
  __shared__ int ws[4];
  if (lane == 63) ws[wv] = s;
  __syncthreads();
  int woff = 0;
  for (int k=0;k<wv;++k) woff += ws[k];
  int off = s - v + woff + bsum[blockIdx.x];
  if (i < NN){ row_start[i] = off; cursor[i] = off; }
  if (i == 0) row_start[NN] = ET;
}

__global__ void fill_k(const int* __restrict__ ei, int* __restrict__ cursor,
                       int* __restrict__ srcs){
  int e = blockIdx.x*256 + threadIdx.x;
  if (e < ET){
    int s, d;
    if (e < EE){ s = ei[e]; d = ei[EE + e]; }
    else       { s = e - EE; d = s; }
    int pos = atomicAdd(&cursor[d], 1);
    srcs[pos] = s;
  }
}

// ---------------- GEMM (f32 out): C[N,128] = A @ W, fused rowdot ----------
__global__ __launch_bounds__(256) void gemm128_f_k(const float* __restrict__ A,
                                                   const float* __restrict__ W,
                                                   const float* __restrict__ as,
                                                   const float* __restrict__ ad,
                                                   float* __restrict__ C,
                                                   float* __restrict__ hs,
                                                   float* __restrict__ hd){
  __shared__ float Alt[DD*64];
  __shared__ float Wl[DD*64];
  int tid = threadIdx.x;
  int rbase = blockIdx.x*64;
  for (int it=0; it<8; ++it){
    int i = it*256 + tid;
    int r = i & 63;
    int c4 = i >> 6;
    float4 v = {0.f,0.f,0.f,0.f};
    if (rbase + r < NN) v = *(const float4*)(A + (size_t)(rbase+r)*DD + c4*4);
    Alt[(c4*4+0)*64 + r] = v.x;
    Alt[(c4*4+1)*64 + r] = v.y;
    Alt[(c4*4+2)*64 + r] = v.z;
    Alt[(c4*4+3)*64 + r] = v.w;
  }
  int ry = tid >> 4, cx = tid & 15;
  float hsum[4] = {0.f,0.f,0.f,0.f};
  float hdsum[4] = {0.f,0.f,0.f,0.f};
  for (int jt=0; jt<2; ++jt){
    __syncthreads();
    for (int it=0; it<8; ++it){
      int i = it*256 + tid;
      int k = i >> 4, c4 = i & 15;
      *(float4*)(Wl + k*64 + c4*4) = *(const float4*)(W + k*DD + jt*64 + c4*4);
    }
    __syncthreads();
    float acc[4][4] = {};
    #pragma unroll 8
    for (int k=0;k<DD;++k){
      float4 av = *(const float4*)(Alt + k*64 + ry*4);
      float4 wv = *(const float4*)(Wl + k*64 + cx*4);
      float a[4] = {av.x, av.y, av.z, av.w};
      float b[4] = {wv.x, wv.y, wv.z, wv.w};
      #pragma unroll
      for (int ii=0;ii<4;++ii)
        #pragma unroll
        for (int jj=0;jj<4;++jj)
          acc[ii][jj] += a[ii]*b[jj];
    }
    float4 a_s = *(const float4*)(as + jt*64 + cx*4);
    float4 a_d = *(const float4*)(ad + jt*64 + cx*4);
    #pragma unroll
    for (int ii=0;ii<4;++ii){
      float ds = acc[ii][0]*a_s.x + acc[ii][1]*a_s.y + acc[ii][2]*a_s.z + acc[ii][3]*a_s.w;
      float dd = acc[ii][0]*a_d.x + acc[ii][1]*a_d.y + acc[ii][2]*a_d.z + acc[ii][3]*a_d.w;
      #pragma unroll
      for (int o=1;o<16;o<<=1){ ds += __shfl_xor(ds,o); dd += __shfl_xor(dd,o); }
      hsum[ii] += ds; hdsum[ii] += dd;
    }
    #pragma unroll
    for (int ii=0;ii<4;++ii){
      int r = rbase + ry*4 + ii;
      if (r < NN){
        float4 o = {acc[ii][0], acc[ii][1], acc[ii][2], acc[ii][3]};
        *(float4*)(C + (size_t)r*DD + jt*64 + cx*4) = o;
      }
    }
  }
  if (cx == 0){
    #pragma unroll
    for (int ii=0;ii<4;++ii){
      int r = rbase + ry*4 + ii;
      if (r < NN){ hs[r] = hsum[ii]; hd[r] = hdsum[ii]; }
    }
  }
}

// ---------------- GEMM (fp16 out) : same, stores fp16 C -------------------
__global__ __launch_bounds__(256) void gemm128_h_k(const float* __restrict__ A,
                                                   const float* __restrict__ W,
                                                   const float* __restrict__ as,
                                                   const float* __restrict__ ad,
                                                   u16* __restrict__ Ch,
                                                   float* __restrict__ hs,
                                                   float* __restrict__ hd){
  __shared__ float Alt[DD*64];
  __shared__ float Wl[DD*64];
  int tid = threadIdx.x;
  int rbase = blockIdx.x*64;
  for (int it=0; it<8; ++it){
    int i = it*256 + tid;
    int r = i & 63;
    int c4 = i >> 6;
    float4 v = {0.f,0.f,0.f,0.f};
    if (rbase + r < NN) v = *(const float4*)(A + (size_t)(rbase+r)*DD + c4*4);
    Alt[(c4*4+0)*64 + r] = v.x;
    Alt[(c4*4+1)*64 + r] = v.y;
    Alt[(c4*4+2)*64 + r] = v.z;
    Alt[(c4*4+3)*64 + r] = v.w;
  }
  int ry = tid >> 4, cx = tid & 15;
  float hsum[4] = {0.f,0.f,0.f,0.f};
  float hdsum[4] = {0.f,0.f,0.f,0.f};
  for (int jt=0; jt<2; ++jt){
    __syncthreads();
    for (int it=0; it<8; ++it){
      int i = it*256 + tid;
      int k = i >> 4, c4 = i & 15;
      *(float4*)(Wl + k*64 + c4*4) = *(const float4*)(W + k*DD + jt*64 + c4*4);
    }
    __syncthreads();
    float acc[4][4] = {};
    #pragma unroll 8
    for (int k=0;k<DD;++k){
      float4 av = *(const float4*)(Alt + k*64 + ry*4);
      float4 wv = *(const float4*)(Wl + k*64 + cx*4);
      float a[4] = {av.x, av.y, av.z, av.w};
      float b[4] = {wv.x, wv.y, wv.z, wv.w};
      #pragma unroll
      for (int ii=0;ii<4;++ii)
        #pragma unroll
        for (int jj=0;jj<4;++jj)
          acc[ii][jj] += a[ii]*b[jj];
    }
    float4 a_s = *(const float4*)(as + jt*64 + cx*4);
    float4 a_d = *(const float4*)(ad + jt*64 + cx*4);
    #pragma unroll
    for (int ii=0;ii<4;++ii){
      float ds = acc[ii][0]*a_s.x + acc[ii][1]*a_s.y + acc[ii][2]*a_s.z + acc[ii][3]*a_s.w;
      float dd = acc[ii][0]*a_d.x + acc[ii][1]*a_d.y + acc[ii][2]*a_d.z + acc[ii][3]*a_d.w;
      #pragma unroll
      for (int o=1;o<16;o<<=1){ ds += __shfl_xor(ds,o); dd += __shfl_xor(dd,o); }
      hsum[ii] += ds; hdsum[ii] += dd;
    }
    #pragma unroll
    for (int ii=0;ii<4;++ii){
      int r = rbase + ry*4 + ii;
      if (r < NN){
        ushort4 o;
        o.x = f2h(acc[ii][0]); o.y = f2h(acc[ii][1]);
        o.z = f2h(acc[ii][2]); o.w = f2h(acc[ii][3]);
        *(ushort4*)(Ch + (size_t)r*DD + jt*64 + cx*4) = o;
      }
    }
  }
  if (cx == 0){
    #pragma unroll
    for (int ii=0;ii<4;++ii){
      int r = rbase + ry*4 + ii;
      if (r < NN){ hs[r] = hsum[ii]; hd[r] = hdsum[ii]; }
    }
  }
}

// ---- agg (f32 h): one wave per node, half-wave parity split (round-2) ----
__global__ __launch_bounds__(256) void gat_agg_f_k(const float* __restrict__ h,
                                                   const float* __restrict__ hs,
                                                   const float* __restrict__ hd,
                                                   const int* __restrict__ row_start,
                                                   const int* __restrict__ srcs,
                                                   const float* __restrict__ bias,
                                                   float* __restrict__ out){
  int node = blockIdx.x*4 + (threadIdx.x >> 6);
  int lane = threadIdx.x & 63;
  if (node >= NN) return;
  int half = lane >> 5;
  int hl   = lane & 31;
  int beg = row_start[node], end = row_start[node+1];
  float hdn = hd[node];
  float m = -INFINITY, denom = 0.f;
  float4 acc = {0.f,0.f,0.f,0.f};
  for (int c=beg; c<end; c+=64){
    int nc = min(64, end-c);
    float e = -INFINITY; int src = 0;
    if (lane < nc){
      src = srcs[c+lane];
      float t = hs[src] + hdn;
      e = (t >= 0.f) ? t : SLOPE*t;
    }
    float cm = e;
    #pragma unroll
    for (int o=32;o;o>>=1) cm = fmaxf(cm, __shfl_xor(cm,o));
    float nm = fmaxf(m, cm);
    float w = (lane < nc) ? expf(e - nm) : 0.f;
    float cs = w;
    #pragma unroll
    for (int o=32;o;o>>=1) cs += __shfl_xor(cs,o);
    float scale = expf(m - nm);
    denom = denom*scale + cs;
    acc.x *= scale; acc.y *= scale; acc.z *= scale; acc.w *= scale;
    m = nm;
    int nh = (nc + 1 - half) >> 1;
    for (int i=0;i<nh;++i){
      int j = 2*i + half;
      float wi = __shfl(w, j);
      int   si = __shfl(src, j);
      float4 hv = *(const float4*)(h + (size_t)si*DD + hl*4);
      acc.x += wi*hv.x; acc.y += wi*hv.y; acc.z += wi*hv.z; acc.w += wi*hv.w;
    }
  }
  acc.x += __shfl_xor(acc.x, 32);
  acc.y += __shfl_xor(acc.y, 32);
  acc.z += __shfl_xor(acc.z, 32);
  acc.w += __shfl_xor(acc.w, 32);
  if (half == 0){
    float inv = 1.f/denom;
    float4 b4 = *(const float4*)(bias + hl*4);
    float4 o4;
    o4.x = fmaxf(acc.x*inv + b4.x, 0.f);
    o4.y = fmaxf(acc.y*inv + b4.y, 0.f);
    o4.z = fmaxf(acc.z*inv + b4.z, 0.f);
    o4.w = fmaxf(acc.w*inv + b4.w, 0.f);
    *(float4*)(out + (size_t)node*DD + hl*4) = o4;
  }
}

// ---- agg (fp16 h): same structure, uint2 (4 fp16) per lane --------------
__global__ __launch_bounds__(256) void gat_agg_h_k(const u16* __restrict__ hh,
                                                   const float* __restrict__ hs,
                                                   const float* __restrict__ hd,
                                                   const int* __restrict__ row_start,
                                                   const int* __restrict__ srcs,
                                                   const float* __restrict__ bias,
                                                   float* __restrict__ out){
  int node = blockIdx.x*4 + (threadIdx.x >> 6);
  int lane = threadIdx.x & 63;
  if (node >= NN) return;
  int half = lane >> 5;
  int hl   = lane & 31;
  int beg = row_start[node], end = row_start[node+1];
  float hdn = hd[node];
  float m = -INFINITY, denom = 0.f;
  float a0=0.f, a1=0.f, a2=0.f, a3=0.f;
  for (int c=beg; c<end; c+=64){
    int nc = min(64, end-c);
    float e = -INFINITY; int src = 0;
    if (lane < nc){
      src = srcs[c+lane];
      float t = hs[src] + hdn;
      e = (t >= 0.f) ? t : SLOPE*t;
    }
    float cm = e;
    #pragma unroll
    for (int o=32;o;o>>=1) cm = fmaxf(cm, __shfl_xor(cm,o));
    float nm = fmaxf(m, cm);
    float w = (lane < nc) ? expf(e - nm) : 0.f;
    float cs = w;
    #pragma unroll
    for (int o=32;o;o>>=1) cs += __shfl_xor(cs,o);
    float scale = expf(m - nm);
    denom = denom*scale + cs;
    a0 *= scale; a1 *= scale; a2 *= scale; a3 *= scale;
    m = nm;
    int nh = (nc + 1 - half) >> 1;
    for (int i=0;i<nh;++i){
      int j = 2*i + half;
      float wi = __shfl(w, j);
      int   si = __shfl(src, j);
      uint2 hv = *(const uint2*)(hh + (size_t)si*DD + hl*4);
      a0 += wi*hlo(hv.x); a1 += wi*hhi(hv.x);
      a2 += wi*hlo(hv.y); a3 += wi*hhi(hv.y);
    }
  }
  a0 += __shfl_xor(a0, 32);
  a1 += __shfl_xor(a1, 32);
  a2 += __shfl_xor(a2, 32);
  a3 += __shfl_xor(a3, 32);
  if (half == 0){
    float inv = 1.f/denom;
    float4 b4 = *(const float4*)(bias + hl*4);
    float4 o4;
    o4.x = fmaxf(a0*inv + b4.x, 0.f);
    o4.y = fmaxf(a1*inv + b4.y, 0.f);
    o4.z = fmaxf(a2*inv + b4.z, 0.f);
    o4.w = fmaxf(a3*inv + b4.w, 0.f);
    *(float4*)(out + (size_t)node*DD + hl*4) = o4;
  }
}

// ---- fused tail: pool + lin0 + lin1(+energy,residual) + lins + head -----
// one 128-thread block per graph (all deps are per-graph-row)
__global__ __launch_bounds__(128) void tail_k(const float* __restrict__ h,
                                              const int* __restrict__ gstart,
                                              const float* __restrict__ energy,
                                              const float* __restrict__ W0, const float* __restrict__ b0,
                                              const float* __restrict__ W1, const float* __restrict__ b1,
                                              const float* __restrict__ W2, const float* __restrict__ b2,
                                              const float* __restrict__ W3, const float* __restrict__ b3,
                                              float* __restrict__ out){
  __shared__ float row[DD];
  __shared__ float buf[DD];
  int gr = blockIdx.x, j = threadIdx.x;
  int beg = gstart[gr], end = gstart[gr+1];
  float s = 0.f;
  for (int n=beg; n<end; ++n) s += h[(size_t)n*DD + j];
  row[j] = s;                               // pooled g
  __syncthreads();
  float acc = 0.f;                          // y = relu(g@W0+b0)
  #pragma unroll 8
  for (int k=0;k<DD;++k) acc += row[k]*W0[k*DD + j];
  float y = fmaxf(acc + b0[j], 0.f);
  buf[j] = y;
  __syncthreads();
  acc = 0.f;                                // z = relu(cat(y,e)@W1+b1) + y
  #pragma unroll 8
  for (int k=0;k<DD;++k) acc += buf[k]*W1[k*DD + j];
  acc += energy[gr]*W1[DD*DD + j];
  float z = fmaxf(acc + b1[j], 0.f) + y;
  __syncthreads();
  row[j] = z;
  __syncthreads();
  acc = 0.f;                                // z2 = relu(z@W2+b2)
  #pragma unroll 8
  for (int k=0;k<DD;++k) acc += row[k]*W2[k*DD + j];
  float z2 = fmaxf(acc + b2[j], 0.f);
  buf[j] = z2;
  __syncthreads();
  if (j < 64){                              // head: W3[128,2] + log_softmax
    float z0 = buf[j], z1 = buf[j+64];
    float l0 = z0*W3[j*2]     + z1*W3[(j+64)*2];
    float l1 = z0*W3[j*2 + 1] + z1*W3[(j+64)*2 + 1];
    #pragma unroll
    for (int o=32;o;o>>=1){ l0 += __shfl_xor(l0,o); l1 += __shfl_xor(l1,o); }
    if (j == 0){
      l0 += b3[0]; l1 += b3[1];
      float mx = fmaxf(l0, l1);
      float lse = mx + logf(expf(l0-mx) + expf(l1-mx));
      out[gr*2]   = l0 - lse;
      out[gr*2+1] = l1 - lse;
    }
  }
}

extern "C" void kernel_launch(void* const* d_in, const int* in_sizes, int n_in,
                              void* d_out, int out_size, void* d_ws, size_t ws_size,
                              hipStream_t stream) {
  const float* x      = (const float*)d_in[0];
  const float* energy = (const float*)d_in[1];
  const float* W1     = (const float*)d_in[2];
  const float* as1    = (const float*)d_in[3];
  const float* ad1    = (const float*)d_in[4];
  const float* b1     = (const float*)d_in[5];
  const float* Ws     = (const float*)d_in[6];
  const float* ass    = (const float*)d_in[7];
  const float* ads    = (const float*)d_in[8];
  const float* bs     = (const float*)d_in[9];
  const float* lin0_W = (const float*)d_in[10];
  const float* lin0_b = (const float*)d_in[11];
  const float* lin1_W = (const float*)d_in[12];
  const float* lin1_b = (const float*)d_in[13];
  const float* lins_W = (const float*)d_in[14];
  const float* lins_b = (const float*)d_in[15];
  const float* lin3_W = (const float*)d_in[16];
  const float* lin3_b = (const float*)d_in[17];
  const int*   ei     = (const int*)d_in[18];
  const int*   batchs = (const int*)d_in[19];
  float* out = (float*)d_out;

  char* wp = (char*)d_ws;
  auto alloc = [&](size_t bytes)->void*{
    void* p = (void*)wp;
    wp += (bytes + 255) & ~(size_t)255;
    return p;
  };
  float* hA        = (float*)alloc((size_t)NN*DD*4);   // agg output (f32)
  float* hB        = (float*)alloc((size_t)NN*DD*4);   // gemm out f32 (layers 1,2)
  u16*   hHf       = (u16*)hB;                         // gemm out fp16 (layers 3,4) — same storage, disjoint lifetime
  float* hs        = (float*)alloc((size_t)NN*4);
  float* hd        = (float*)alloc((size_t)NN*4);
  int*   cnt       = (int*)alloc((size_t)NN*4);
  int*   row_start = (int*)alloc((size_t)(NN+1)*4);
  int*   cursor    = (int*)alloc((size_t)NN*4);
  int*   srcs      = (int*)alloc((size_t)ET*4);
  int*   gstart    = (int*)alloc((size_t)(GG+1)*4);
  int*   bsum      = (int*)alloc((size_t)256*4);

  const int NB_N  = (NN + 255)/256;     // 196
  const int NB_E  = (ET + 255)/256;     // 3321
  const int NB_W  = (NN + 3)/4;         // 12500 (wave per node)
  const int NB_G  = (NN + 63)/64;       // 782 gemm blocks

  // CSR + graph boundaries
  init_k<<<NB_N, 256, 0, stream>>>(batchs, cnt, gstart);
  count_k<<<NB_E, 256, 0, stream>>>(ei, cnt);
  blocksum_k<<<NB_N, 256, 0, stream>>>(cnt, bsum);
  scanb_k<<<1, 256, 0, stream>>>(bsum, NB_N);
  scatter_k<<<NB_N, 256, 0, stream>>>(cnt, bsum, row_start, cursor);
  fill_k<<<NB_E, 256, 0, stream>>>(ei, cursor, srcs);

  // layers 1,2: f32 gather path (exact round-2 numerics)
  gemm128_f_k<<<NB_G, 256, 0, stream>>>(x, W1, as1, ad1, hB, hs, hd);
  gat_agg_f_k<<<NB_W, 256, 0, stream>>>(hB, hs, hd, row_start, srcs, b1, hA);
  gemm128_f_k<<<NB_G, 256, 0, stream>>>(hA, Ws, ass, ads, hB, hs, hd);
  gat_agg_f_k<<<NB_W, 256, 0, stream>>>(hB, hs, hd, row_start, srcs, bs, hA);

  // layers 3,4: fp16 gather path (halved gather bytes; alphas stay f32)
  gemm128_h_k<<<NB_G, 256, 0, stream>>>(hA, Ws + (size_t)1*DD*DD, ass + DD, ads + DD,
                                        hHf, hs, hd);
  gat_agg_h_k<<<NB_W, 256, 0, stream>>>(hHf, hs, hd, row_start, srcs, bs + DD, hA);
  gemm128_h_k<<<NB_G, 256, 0, stream>>>(hA, Ws + (size_t)2*DD*DD, ass + 2*DD, ads + 2*DD,
                                        hHf, hs, hd);
  gat_agg_h_k<<<NB_W, 256, 0, stream>>>(hHf, hs, hd, row_start, srcs, bs + 2*DD, hA);

  // fused tail
  tail_k<<<GG, 128, 0, stream>>>(hA, gstart, energy,
                                 lin0_W, lin0_b, lin1_W, lin1_b,
                                 lins_W, lins_b, lin3_W, lin3_b, out);
}

// Round 6
// 550.581 us; speedup vs baseline: 1.4604x; 1.0667x over previous
//
#include <hip/hip_runtime.h>
#include <math.h>

#define NN 50000
#define EE 800000
#define ET 850000   // EE + NN (self loops appended)
#define DD 128
#define GG 1000
#define SLOPE 0.2f

#define KB   2048          // edges per phase-A block
#define NBA  416           // ceil(ET/KB)
#define BSZ  4096          // positions per bucket
#define NBUK 208           // ceil(ET/BSZ)

typedef unsigned int  u32;
typedef unsigned short u16;

// fp16 pack/unpack (hardware cvt, round-to-nearest-even)
__device__ __forceinline__ u16 f2h(float f){
  return __builtin_bit_cast(unsigned short, (_Float16)f);
}
__device__ __forceinline__ float hlo(u32 d){
  return (float)__builtin_bit_cast(_Float16, (unsigned short)(d & 0xFFFFu));
}
__device__ __forceinline__ float hhi(u32 d){
  return (float)__builtin_bit_cast(_Float16, (unsigned short)(d >> 16));
}

// ---------------- init: cnt=0, bcur=0, graph boundaries ----------------
__global__ void init_k(const int* __restrict__ batchs, int* __restrict__ cnt,
                       int* __restrict__ gstart, int* __restrict__ bcur){
  int n = blockIdx.x*256 + threadIdx.x;
  if (n < NBUK) bcur[n] = 0;
  if (n < NN){
    cnt[n] = 0;
    int b = batchs[n];
    int prev = n ? batchs[n-1] : -1;
    for (int g = prev+1; g <= b; ++g) gstart[g] = n;
    if (n == NN-1){
      for (int g = b+1; g <= GG; ++g) gstart[g] = NN;
    }
  }
}

// count + per-edge rank (atomicAdd return) — rank makes pos computable later
__global__ void count_k(const int* __restrict__ ei, int* __restrict__ cnt,
                        int* __restrict__ rank){
  int e = blockIdx.x*256 + threadIdx.x;
  if (e < ET){
    int d = (e < EE) ? ei[EE + e] : (e - EE);
    rank[e] = atomicAdd(&cnt[d], 1);
  }
}

__global__ __launch_bounds__(256) void blocksum_k(const int* __restrict__ cnt,
                                                  int* __restrict__ bsum){
  int i = blockIdx.x*256 + threadIdx.x;
  int v = (i < NN) ? cnt[i] : 0;
  #pragma unroll
  for (int o=32;o;o>>=1) v += __shfl_xor(v,o);
  __shared__ int ws[4];
  if ((threadIdx.x & 63) == 0) ws[threadIdx.x>>6] = v;
  __syncthreads();
  if (threadIdx.x == 0) bsum[blockIdx.x] = ws[0]+ws[1]+ws[2]+ws[3];
}

__global__ __launch_bounds__(256) void scanb_k(int* __restrict__ bsum, int nb){
  int tid = threadIdx.x;
  int v = (tid < nb) ? bsum[tid] : 0;
  int lane = tid & 63, wv = tid >> 6;
  int s = v;
  #pragma unroll
  for (int o=1;o<64;o<<=1){ int t = __shfl_up(s,o); if (lane>=o) s += t; }
  __shared__ int ws[4];
  if (lane == 63) ws[wv] = s;
  __syncthreads();
  int woff = 0;
  for (int k=0;k<wv;++k) woff += ws[k];
  if (tid < nb) bsum[tid] = s - v + woff;   // exclusive prefix
}

__global__ __launch_bounds__(256) void scatter_k(const int* __restrict__ cnt,
                                                 const int* __restrict__ bsum,
                                                 int* __restrict__ row_start){
  int i = blockIdx.x*256 + threadIdx.x;
  int v = (i < NN) ? cnt[i] : 0;
  int lane = threadIdx.x & 63, wv = threadIdx.x >> 6;
  int s = v;
  #pragma unroll
  for (int o=1;o<64;o<<=1){ int t = __shfl_up(s,o); if (lane>=o) s += t; }
  __shared__ int ws[4];
  if (lane == 63) ws[wv] = s;
  __syncthreads();
  int woff = 0;
  for (int k=0;k<wv;++k) woff += ws[k];
  int off = s - v + woff + bsum[blockIdx.x];
  if (i < NN) row_start[i] = off;
  if (i == 0) row_start[NN] = ET;
}

// ---- phase A: partition (pos,src) pairs into fixed 4096-wide pos-buckets ----
// pos = row_start[dst] + rank is a BIJECTION on [0,ET) -> bucket b=pos>>12
// holds exactly min(4096, ET-(b<<12)) pairs; staging regions are fixed-size.
__global__ __launch_bounds__(256) void partA_k(const int* __restrict__ ei,
                                               const int* __restrict__ rank,
                                               const int* __restrict__ row_start,
                                               int* __restrict__ bcur,
                                               uint2* __restrict__ stage){
  __shared__ uint2 lpairs[KB];          // 16 KB
  __shared__ int lcnt[256], lstart[256], lrun[256], gbase[256];
  __shared__ int ws[4];
  int tid = threadIdx.x;
  int base = blockIdx.x * KB;
  int nE = min(KB, ET - base);
  lcnt[tid] = 0;
  __syncthreads();
  u32 pos_r[KB/256]; u32 src_r[KB/256];
  #pragma unroll
  for (int i=0;i<KB/256;++i){
    int e = base + i*256 + tid;
    u32 p = 0xFFFFFFFFu, s = 0;
    if (e < ET){
      int d, sr;
      if (e < EE){ sr = ei[e]; d = ei[EE + e]; }
      else       { sr = e - EE; d = sr; }
      p = (u32)(row_start[d] + rank[e]);
      s = (u32)sr;
      atomicAdd(&lcnt[p >> 12], 1);
    }
    pos_r[i] = p; src_r[i] = s;
  }
  __syncthreads();
  // exclusive scan of lcnt over 256 slots (only NBUK used)
  int v = lcnt[tid];
  int lane = tid & 63, wv = tid >> 6;
  int s = v;
  #pragma unroll
  for (int o=1;o<64;o<<=1){ int t = __shfl_up(s,o); if (lane>=o) s += t; }
  if (lane == 63) ws[wv] = s;
  __syncthreads();
  int woff = 0;
  for (int k=0;k<wv;++k) woff += ws[k];
  int excl = s - v + woff;
  lstart[tid] = excl;
  lrun[tid]   = excl;
  gbase[tid]  = (tid < NBUK && v > 0) ? atomicAdd(&bcur[tid], v) : 0;
  __syncthreads();
  // place pairs into LDS grouped by bucket
  #pragma unroll
  for (int i=0;i<KB/256;++i){
    if (pos_r[i] != 0xFFFFFFFFu){
      int b = pos_r[i] >> 12;
      int slot = atomicAdd(&lrun[b], 1);
      lpairs[slot] = make_uint2(pos_r[i], src_r[i]);
    }
  }
  __syncthreads();
  // coalesced run-copy to global staging
  for (int j = tid; j < nE; j += 256){
    uint2 pr = lpairs[j];
    int b = pr.x >> 12;
    int dest = (b << 12) + gbase[b] + (j - lstart[b]);
    stage[dest] = pr;
  }
}

// ---- phase B: assemble each 16KB srcs window in LDS, stream out coalesced ----
__global__ __launch_bounds__(256) void partB_k(const uint2* __restrict__ stage,
                                               int* __restrict__ srcs){
  __shared__ int buf[BSZ];              // 16 KB
  int b = blockIdx.x, tid = threadIdx.x;
  int base = b << 12;
  int n_b = min(BSZ, ET - base);
  for (int j = tid; j < n_b; j += 256){
    uint2 pr = stage[base + j];
    buf[pr.x - base] = (int)pr.y;
  }
  __syncthreads();
  for (int j = tid; j*4 < n_b; j += 256){
    *(int4*)(srcs + base + j*4) = *(const int4*)(buf + j*4);
  }
}

// ---------------- GEMM (f32 out): C[N,128] = A @ W, fused rowdot ----------
__global__ __launch_bounds__(256) void gemm128_f_k(const float* __restrict__ A,
                                                   const float* __restrict__ W,
                                                   const float* __restrict__ as,
                                                   const float* __restrict__ ad,
                                                   float* __restrict__ C,
                                                   float* __restrict__ hs,
                                                   float* __restrict__ hd){
  __shared__ float Alt[DD*64];
  __shared__ float Wl[DD*64];
  int tid = threadIdx.x;
  int rbase = blockIdx.x*64;
  for (int it=0; it<8; ++it){
    int i = it*256 + tid;
    int r = i & 63;
    int c4 = i >> 6;
    float4 v = {0.f,0.f,0.f,0.f};
    if (rbase + r < NN) v = *(const float4*)(A + (size_t)(rbase+r)*DD + c4*4);
    Alt[(c4*4+0)*64 + r] = v.x;
    Alt[(c4*4+1)*64 + r] = v.y;
    Alt[(c4*4+2)*64 + r] = v.z;
    Alt[(c4*4+3)*64 + r] = v.w;
  }
  int ry = tid >> 4, cx = tid & 15;
  float hsum[4] = {0.f,0.f,0.f,0.f};
  float hdsum[4] = {0.f,0.f,0.f,0.f};
  for (int jt=0; jt<2; ++jt){
    __syncthreads();
    for (int it=0; it<8; ++it){
      int i = it*256 + tid;
      int k = i >> 4, c4 = i & 15;
      *(float4*)(Wl + k*64 + c4*4) = *(const float4*)(W + k*DD + jt*64 + c4*4);
    }
    __syncthreads();
    float acc[4][4] = {};
    #pragma unroll 8
    for (int k=0;k<DD;++k){
      float4 av = *(const float4*)(Alt + k*64 + ry*4);
      float4 wv = *(const float4*)(Wl + k*64 + cx*4);
      float a[4] = {av.x, av.y, av.z, av.w};
      float b[4] = {wv.x, wv.y, wv.z, wv.w};
      #pragma unroll
      for (int ii=0;ii<4;++ii)
        #pragma unroll
        for (int jj=0;jj<4;++jj)
          acc[ii][jj] += a[ii]*b[jj];
    }
    float4 a_s = *(const float4*)(as + jt*64 + cx*4);
    float4 a_d = *(const float4*)(ad + jt*64 + cx*4);
    #pragma unroll
    for (int ii=0;ii<4;++ii){
      float ds = acc[ii][0]*a_s.x + acc[ii][1]*a_s.y + acc[ii][2]*a_s.z + acc[ii][3]*a_s.w;
      float dd = acc[ii][0]*a_d.x + acc[ii][1]*a_d.y + acc[ii][2]*a_d.z + acc[ii][3]*a_d.w;
      #pragma unroll
      for (int o=1;o<16;o<<=1){ ds += __shfl_xor(ds,o); dd += __shfl_xor(dd,o); }
      hsum[ii] += ds; hdsum[ii] += dd;
    }
    #pragma unroll
    for (int ii=0;ii<4;++ii){
      int r = rbase + ry*4 + ii;
      if (r < NN){
        float4 o = {acc[ii][0], acc[ii][1], acc[ii][2], acc[ii][3]};
        *(float4*)(C + (size_t)r*DD + jt*64 + cx*4) = o;
      }
    }
  }
  if (cx == 0){
    #pragma unroll
    for (int ii=0;ii<4;++ii){
      int r = rbase + ry*4 + ii;
      if (r < NN){ hs[r] = hsum[ii]; hd[r] = hdsum[ii]; }
    }
  }
}

// ---------------- GEMM (fp16 out) : same, stores fp16 C -------------------
__global__ __launch_bounds__(256) void gemm128_h_k(const float* __restrict__ A,
                                                   const float* __restrict__ W,
                                                   const float* __restrict__ as,
                                                   const float* __restrict__ ad,
                                                   u16* __restrict__ Ch,
                                                   float* __restrict__ hs,
                                                   float* __restrict__ hd){
  __shared__ float Alt[DD*64];
  __shared__ float Wl[DD*64];
  int tid = threadIdx.x;
  int rbase = blockIdx.x*64;
  for (int it=0; it<8; ++it){
    int i = it*256 + tid;
    int r = i & 63;
    int c4 = i >> 6;
    float4 v = {0.f,0.f,0.f,0.f};
    if (rbase + r < NN) v = *(const float4*)(A + (size_t)(rbase+r)*DD + c4*4);
    Alt[(c4*4+0)*64 + r] = v.x;
    Alt[(c4*4+1)*64 + r] = v.y;
    Alt[(c4*4+2)*64 + r] = v.z;
    Alt[(c4*4+3)*64 + r] = v.w;
  }
  int ry = tid >> 4, cx = tid & 15;
  float hsum[4] = {0.f,0.f,0.f,0.f};
  float hdsum[4] = {0.f,0.f,0.f,0.f};
  for (int jt=0; jt<2; ++jt){
    __syncthreads();
    for (int it=0; it<8; ++it){
      int i = it*256 + tid;
      int k = i >> 4, c4 = i & 15;
      *(float4*)(Wl + k*64 + c4*4) = *(const float4*)(W + k*DD + jt*64 + c4*4);
    }
    __syncthreads();
    float acc[4][4] = {};
    #pragma unroll 8
    for (int k=0;k<DD;++k){
      float4 av = *(const float4*)(Alt + k*64 + ry*4);
      float4 wv = *(const float4*)(Wl + k*64 + cx*4);
      float a[4] = {av.x, av.y, av.z, av.w};
      float b[4] = {wv.x, wv.y, wv.z, wv.w};
      #pragma unroll
      for (int ii=0;ii<4;++ii)
        #pragma unroll
        for (int jj=0;jj<4;++jj)
          acc[ii][jj] += a[ii]*b[jj];
    }
    float4 a_s = *(const float4*)(as + jt*64 + cx*4);
    float4 a_d = *(const float4*)(ad + jt*64 + cx*4);
    #pragma unroll
    for (int ii=0;ii<4;++ii){
      float ds = acc[ii][0]*a_s.x + acc[ii][1]*a_s.y + acc[ii][2]*a_s.z + acc[ii][3]*a_s.w;
      float dd = acc[ii][0]*a_d.x + acc[ii][1]*a_d.y + acc[ii][2]*a_d.z + acc[ii][3]*a_d.w;
      #pragma unroll
      for (int o=1;o<16;o<<=1){ ds += __shfl_xor(ds,o); dd += __shfl_xor(dd,o); }
      hsum[ii] += ds; hdsum[ii] += dd;
    }
    #pragma unroll
    for (int ii=0;ii<4;++ii){
      int r = rbase + ry*4 + ii;
      if (r < NN){
        ushort4 o;
        o.x = f2h(acc[ii][0]); o.y = f2h(acc[ii][1]);
        o.z = f2h(acc[ii][2]); o.w = f2h(acc[ii][3]);
        *(ushort4*)(Ch + (size_t)r*DD + jt*64 + cx*4) = o;
      }
    }
  }
  if (cx == 0){
    #pragma unroll
    for (int ii=0;ii<4;++ii){
      int r = rbase + ry*4 + ii;
      if (r < NN){ hs[r] = hsum[ii]; hd[r] = hdsum[ii]; }
    }
  }
}

// ---- agg (f32 h): one wave per node, half-wave parity split ----
__global__ __launch_bounds__(256) void gat_agg_f_k(const float* __restrict__ h,
                                                   const float* __restrict__ hs,
                                                   const float* __restrict__ hd,
                                                   const int* __restrict__ row_start,
                                                   const int* __restrict__ srcs,
                                                   const float* __restrict__ bias,
                                                   float* __restrict__ out){
  int node = blockIdx.x*4 + (threadIdx.x >> 6);
  int lane = threadIdx.x & 63;
  if (node >= NN) return;
  int half = lane >> 5;
  int hl   = lane & 31;
  int beg = row_start[node], end = row_start[node+1];
  float hdn = hd[node];
  float m = -INFINITY, denom = 0.f;
  float4 acc = {0.f,0.f,0.f,0.f};
  for (int c=beg; c<end; c+=64){
    int nc = min(64, end-c);
    float e = -INFINITY; int src = 0;
    if (lane < nc){
      src = srcs[c+lane];
      float t = hs[src] + hdn;
      e = (t >= 0.f) ? t : SLOPE*t;
    }
    float cm = e;
    #pragma unroll
    for (int o=32;o;o>>=1) cm = fmaxf(cm, __shfl_xor(cm,o));
    float nm = fmaxf(m, cm);
    float w = (lane < nc) ? expf(e - nm) : 0.f;
    float cs = w;
    #pragma unroll
    for (int o=32;o;o>>=1) cs += __shfl_xor(cs,o);
    float scale = expf(m - nm);
    denom = denom*scale + cs;
    acc.x *= scale; acc.y *= scale; acc.z *= scale; acc.w *= scale;
    m = nm;
    int nh = (nc + 1 - half) >> 1;
    for (int i=0;i<nh;++i){
      int j = 2*i + half;
      float wi = __shfl(w, j);
      int   si = __shfl(src, j);
      float4 hv = *(const float4*)(h + (size_t)si*DD + hl*4);
      acc.x += wi*hv.x; acc.y += wi*hv.y; acc.z += wi*hv.z; acc.w += wi*hv.w;
    }
  }
  acc.x += __shfl_xor(acc.x, 32);
  acc.y += __shfl_xor(acc.y, 32);
  acc.z += __shfl_xor(acc.z, 32);
  acc.w += __shfl_xor(acc.w, 32);
  if (half == 0){
    float inv = 1.f/denom;
    float4 b4 = *(const float4*)(bias + hl*4);
    float4 o4;
    o4.x = fmaxf(acc.x*inv + b4.x, 0.f);
    o4.y = fmaxf(acc.y*inv + b4.y, 0.f);
    o4.z = fmaxf(acc.z*inv + b4.z, 0.f);
    o4.w = fmaxf(acc.w*inv + b4.w, 0.f);
    *(float4*)(out + (size_t)node*DD + hl*4) = o4;
  }
}

// ---- agg (fp16 h): same structure, uint2 (4 fp16) per lane --------------
__global__ __launch_bounds__(256) void gat_agg_h_k(const u16* __restrict__ hh,
                                                   const float* __restrict__ hs,
                                                   const float* __restrict__ hd,
                                                   const int* __restrict__ row_start,
                                                   const int* __restrict__ srcs,
                                                   const float* __restrict__ bias,
                                                   float* __restrict__ out){
  int node = blockIdx.x*4 + (threadIdx.x >> 6);
  int lane = threadIdx.x & 63;
  if (node >= NN) return;
  int half = lane >> 5;
  int hl   = lane & 31;
  int beg = row_start[node], end = row_start[node+1];
  float hdn = hd[node];
  float m = -INFINITY, denom = 0.f;
  float a0=0.f, a1=0.f, a2=0.f, a3=0.f;
  for (int c=beg; c<end; c+=64){
    int nc = min(64, end-c);
    float e = -INFINITY; int src = 0;
    if (lane < nc){
      src = srcs[c+lane];
      float t = hs[src] + hdn;
      e = (t >= 0.f) ? t : SLOPE*t;
    }
    float cm = e;
    #pragma unroll
    for (int o=32;o;o>>=1) cm = fmaxf(cm, __shfl_xor(cm,o));
    float nm = fmaxf(m, cm);
    float w = (lane < nc) ? expf(e - nm) : 0.f;
    float cs = w;
    #pragma unroll
    for (int o=32;o;o>>=1) cs += __shfl_xor(cs,o);
    float scale = expf(m - nm);
    denom = denom*scale + cs;
    a0 *= scale; a1 *= scale; a2 *= scale; a3 *= scale;
    m = nm;
    int nh = (nc + 1 - half) >> 1;
    for (int i=0;i<nh;++i){
      int j = 2*i + half;
      float wi = __shfl(w, j);
      int   si = __shfl(src, j);
      uint2 hv = *(const uint2*)(hh + (size_t)si*DD + hl*4);
      a0 += wi*hlo(hv.x); a1 += wi*hhi(hv.x);
      a2 += wi*hlo(hv.y); a3 += wi*hhi(hv.y);
    }
  }
  a0 += __shfl_xor(a0, 32);
  a1 += __shfl_xor(a1, 32);
  a2 += __shfl_xor(a2, 32);
  a3 += __shfl_xor(a3, 32);
  if (half == 0){
    float inv = 1.f/denom;
    float4 b4 = *(const float4*)(bias + hl*4);
    float4 o4;
    o4.x = fmaxf(a0*inv + b4.x, 0.f);
    o4.y = fmaxf(a1*inv + b4.y, 0.f);
    o4.z = fmaxf(a2*inv + b4.z, 0.f);
    o4.w = fmaxf(a3*inv + b4.w, 0.f);
    *(float4*)(out + (size_t)node*DD + hl*4) = o4;
  }
}

// ---- fused tail: pool + lin0 + lin1(+energy,residual) + lins + head -----
__global__ __launch_bounds__(128) void tail_k(const float* __restrict__ h,
                                              const int* __restrict__ gstart,
                                              const float* __restrict__ energy,
                                              const float* __restrict__ W0, const float* __restrict__ b0,
                                              const float* __restrict__ W1, const float* __restrict__ b1,
                                              const float* __restrict__ W2, const float* __restrict__ b2,
                                              const float* __restrict__ W3, const float* __restrict__ b3,
                                              float* __restrict__ out){
  __shared__ float row[DD];
  __shared__ float buf[DD];
  int gr = blockIdx.x, j = threadIdx.x;
  int beg = gstart[gr], end = gstart[gr+1];
  float s = 0.f;
  for (int n=beg; n<end; ++n) s += h[(size_t)n*DD + j];
  row[j] = s;
  __syncthreads();
  float acc = 0.f;
  #pragma unroll 8
  for (int k=0;k<DD;++k) acc += row[k]*W0[k*DD + j];
  float y = fmaxf(acc + b0[j], 0.f);
  buf[j] = y;
  __syncthreads();
  acc = 0.f;
  #pragma unroll 8
  for (int k=0;k<DD;++k) acc += buf[k]*W1[k*DD + j];
  acc += energy[gr]*W1[DD*DD + j];
  float z = fmaxf(acc + b1[j], 0.f) + y;
  __syncthreads();
  row[j] = z;
  __syncthreads();
  acc = 0.f;
  #pragma unroll 8
  for (int k=0;k<DD;++k) acc += row[k]*W2[k*DD + j];
  float z2 = fmaxf(acc + b2[j], 0.f);
  buf[j] = z2;
  __syncthreads();
  if (j < 64){
    float z0 = buf[j], z1 = buf[j+64];
    float l0 = z0*W3[j*2]     + z1*W3[(j+64)*2];
    float l1 = z0*W3[j*2 + 1] + z1*W3[(j+64)*2 + 1];
    #pragma unroll
    for (int o=32;o;o>>=1){ l0 += __shfl_xor(l0,o); l1 += __shfl_xor(l1,o); }
    if (j == 0){
      l0 += b3[0]; l1 += b3[1];
      float mx = fmaxf(l0, l1);
      float lse = mx + logf(expf(l0-mx) + expf(l1-mx));
      out[gr*2]   = l0 - lse;
      out[gr*2+1] = l1 - lse;
    }
  }
}

extern "C" void kernel_launch(void* const* d_in, const int* in_sizes, int n_in,
                              void* d_out, int out_size, void* d_ws, size_t ws_size,
                              hipStream_t stream) {
  const float* x      = (const float*)d_in[0];
  const float* energy = (const float*)d_in[1];
  const float* W1     = (const float*)d_in[2];
  const float* as1    = (const float*)d_in[3];
  const float* ad1    = (const float*)d_in[4];
  const float* b1     = (const float*)d_in[5];
  const float* Ws     = (const float*)d_in[6];
  const float* ass    = (const float*)d_in[7];
  const float* ads    = (const float*)d_in[8];
  const float* bs     = (const float*)d_in[9];
  const float* lin0_W = (const float*)d_in[10];
  const float* lin0_b = (const float*)d_in[11];
  const float* lin1_W = (const float*)d_in[12];
  const float* lin1_b = (const float*)d_in[13];
  const float* lins_W = (const float*)d_in[14];
  const float* lins_b = (const float*)d_in[15];
  const float* lin3_W = (const float*)d_in[16];
  const float* lin3_b = (const float*)d_in[17];
  const int*   ei     = (const int*)d_in[18];
  const int*   batchs = (const int*)d_in[19];
  float* out = (float*)d_out;

  char* wp = (char*)d_ws;
  auto alloc = [&](size_t bytes)->void*{
    void* p = (void*)wp;
    wp += (bytes + 255) & ~(size_t)255;
    return p;
  };
  float* hA        = (float*)alloc((size_t)NN*DD*4);   // agg output (f32)
  float* hB        = (float*)alloc((size_t)NN*DD*4);   // gemm out f32 (layers 1,2)
  u16*   hHf       = (u16*)hB;                         // fp16 view (layers 3,4)
  float* hs        = (float*)alloc((size_t)NN*4);
  float* hd        = (float*)alloc((size_t)NN*4);
  int*   cnt       = (int*)alloc((size_t)NN*4);
  int*   row_start = (int*)alloc((size_t)(NN+1)*4);
  int*   rank      = (int*)alloc((size_t)ET*4);
  int*   srcs      = (int*)alloc((size_t)ET*4);
  uint2* stage     = (uint2*)alloc((size_t)NBUK*BSZ*8);
  int*   bcur      = (int*)alloc((size_t)NBUK*4);
  int*   gstart    = (int*)alloc((size_t)(GG+1)*4);
  int*   bsum      = (int*)alloc((size_t)256*4);

  const int NB_N  = (NN + 255)/256;     // 196
  const int NB_E  = (ET + 255)/256;     // 3321
  const int NB_W  = (NN + 3)/4;         // 12500 (wave per node)
  const int NB_G  = (NN + 63)/64;       // 782 gemm blocks

  // CSR + graph boundaries (two-phase bucketed scatter)
  init_k<<<NB_N, 256, 0, stream>>>(batchs, cnt, gstart, bcur);
  count_k<<<NB_E, 256, 0, stream>>>(ei, cnt, rank);
  blocksum_k<<<NB_N, 256, 0, stream>>>(cnt, bsum);
  scanb_k<<<1, 256, 0, stream>>>(bsum, NB_N);
  scatter_k<<<NB_N, 256, 0, stream>>>(cnt, bsum, row_start);
  partA_k<<<NBA, 256, 0, stream>>>(ei, rank, row_start, bcur, stage);
  partB_k<<<NBUK, 256, 0, stream>>>(stage, srcs);

  // layers 1,2: f32 gather path
  gemm128_f_k<<<NB_G, 256, 0, stream>>>(x, W1, as1, ad1, hB, hs, hd);
  gat_agg_f_k<<<NB_W, 256, 0, stream>>>(hB, hs, hd, row_start, srcs, b1, hA);
  gemm128_f_k<<<NB_G, 256, 0, stream>>>(hA, Ws, ass, ads, hB, hs, hd);
  gat_agg_f_k<<<NB_W, 256, 0, stream>>>(hB, hs, hd, row_start, srcs, bs, hA);

  // layers 3,4: fp16 gather path (alphas stay f32)
  gemm128_h_k<<<NB_G, 256, 0, stream>>>(hA, Ws + (size_t)1*DD*DD, ass + DD, ads + DD,
                                        hHf, hs, hd);
  gat_agg_h_k<<<NB_W, 256, 0, stream>>>(hHf, hs, hd, row_start, srcs, bs + DD, hA);
  gemm128_h_k<<<NB_G, 256, 0, stream>>>(hA, Ws + (size_t)2*DD*DD, ass + 2*DD, ads + 2*DD,
                                        hHf, hs, hd);
  gat_agg_h_k<<<NB_W, 256, 0, stream>>>(hHf, hs, hd, row_start, srcs, bs + 2*DD, hA);

  // fused tail
  tail_k<<<GG, 128, 0, stream>>>(hA, gstart, energy,
                                 lin0_W, lin0_b, lin1_W, lin1_b,
                                 lins_W, lins_b, lin3_W, lin3_b, out);
}